// Round 4
// baseline (118.029 us; speedup 1.0000x reference)
//
#include <hip/hip_runtime.h>
#include <hip/hip_fp16.h>

#define IN_DIM 8192
#define OUT_DIM 8192
#define BATCH 2048
#define TPB 1024                     // 16 waves/block, 4 waves/SIMD
#define RPB 8                        // rows per block; grid = 2048/8 = 256 = 1 block/CU
#define NQ (OUT_DIM / 4 / TPB)       // 2 float4-output quads per thread per row
#define NSTG (IN_DIM / 4 / TPB)      // 2 direct-to-LDS 16B loads per thread per row
#define NBUF 3                       // triple buffer -> DMA depth 2 (96 KB LDS)

typedef float fvec4 __attribute__((ext_vector_type(4)));

#define GLOAD_LDS16(gp, lp)                                                        \
    __builtin_amdgcn_global_load_lds(                                              \
        (const __attribute__((address_space(1))) unsigned int*)(gp),               \
        (__attribute__((address_space(3))) unsigned int*)(lp), 16, 0, 0)

#define MEMFENCE() asm volatile("" ::: "memory")

// ---------------------------------------------------------------------------
// Kernel 1: softmax(16) -> 4 affine coeffs {1,a,b,ab} in FP32:
//   pidx[j] = (idx_a*4) | (idx_b*4 << 16)   -- BYTE offsets (idx<8192 -> *4 < 32768)
//   pcA[j]  = float2(c0, ca), pcB[j] = float2(cb, cab)
// ---------------------------------------------------------------------------
__global__ __launch_bounds__(64) void coeff_kernel(
    const float* __restrict__ w,
    const int* __restrict__ idx_a,
    const int* __restrict__ idx_b,
    int* __restrict__ pidx,
    float2* __restrict__ pcA,
    float2* __restrict__ pcB)
{
    int j = blockIdx.x * 64 + threadIdx.x;     // grid exact: 8192 = 128*64

    const float4* w4 = (const float4*)(w + (size_t)j * 16);
    float4 q0 = w4[0], q1 = w4[1], q2 = w4[2], q3 = w4[3];
    float wv[16] = { q0.x, q0.y, q0.z, q0.w,
                     q1.x, q1.y, q1.z, q1.w,
                     q2.x, q2.y, q2.z, q2.w,
                     q3.x, q3.y, q3.z, q3.w };

    float m = -1e30f;
#pragma unroll
    for (int k = 0; k < 16; ++k) m = fmaxf(m, wv[k]);
    float s = 0.f;
#pragma unroll
    for (int k = 0; k < 16; ++k) { wv[k] = __expf(wv[k] - m); s += wv[k]; }
    float inv = 1.0f / s;
#pragma unroll
    for (int k = 0; k < 16; ++k) wv[k] *= inv;

    float c0  = wv[8] + wv[9] + wv[10] + wv[11] + wv[12] + wv[13] + wv[14] + wv[15];
    float ca  = wv[2] + wv[3] + wv[6] + wv[7] - wv[8] - wv[9] - wv[12] - wv[13];
    float cb  = wv[4] + wv[5] + wv[6] + wv[7] - wv[8] - wv[9] - wv[10] - wv[11];
    float cab = wv[1] - wv[2] - wv[4] - 2.f * wv[6] - wv[7]
              + wv[8] + 2.f * wv[9] + wv[11] + wv[13] - wv[14];

    pidx[j] = ((idx_a[j] << 2) & 0xffff) | (idx_b[j] << 18);
    pcA[j]  = make_float2(c0, ca);
    pcB[j]  = make_float2(cb, cab);
}

// ---------------------------------------------------------------------------
// Kernel 2: 8 rows per block, 1 block/CU (grid=256). Coeffs register-resident
// (row-invariant, loaded once: 40 VGPRs). Triple-buffered LDS staging via
// global_load_lds with DEPTH-2 prefetch:
//
//   prologue: DMA(0)->buf0, DMA(1)->buf1
//   iter r:  bar_A  (all waves done reading buf[(r+2)%3] = row r-1's buffer)
//            issue DMA(row r+2 -> buf[(r+2)%3])
//            s_waitcnt vmcnt(N)  -- counted: retires exactly DMA(r), which was
//                                   issued TWO periods ago (slack = 2 periods)
//            bar_B  (LDS row r valid for all waves)
//            compute row r from buf[r%3], NQ nontemporal float4 stores
//
// vmcnt rule (vmem FIFO retires in issue order): N = #vmem instrs issued
// AFTER DMA(r). Steady state r in [2, RPB-3]:
//   st(r-2) x2 + DMA(r+1) x2 + st(r-1) x2 + DMA(r+2) x2 = 8.
// Edges: r=0 -> 4 (DMA1,DMA2; also retires the 10 older coeff loads),
//        r=1 -> 6 (DMA2, st0, DMA3),  r=RPB-2 -> 6 (st, DMA, st),
//        r=RPB-1 -> 4 (st, st). Never drained to 0 mid-loop.
//
// Rationale: at saturation, HBM delivers each CU's 32KB row-read over ~one
// full period, so depth-1 prefetch completes with ZERO slack and every
// jitter event stretches the steady-state period (R3: 22K cy vs 12.8K BW
// floor). Depth-2 gives a full spare period of slack to absorb transients.
// ---------------------------------------------------------------------------
__global__ __launch_bounds__(TPB, 4) void logic_kernel(
    const float* __restrict__ x,
    const int* __restrict__ pidx,
    const float2* __restrict__ pcA,
    const float2* __restrict__ pcB,
    float* __restrict__ out)
{
    __shared__ float xrow[NBUF][IN_DIM];     // 96 KB -> 1 block/CU

    const int tid  = threadIdx.x;
    const int row0 = blockIdx.x * RPB;

    // ---- coeffs ONCE into registers (reused for all 8 rows) ----
    const int4*   pidx4 = (const int4*)pidx;
    const float4* pA4   = (const float4*)pcA;
    const float4* pB4   = (const float4*)pcB;

    int4   pi[NQ];
    float4 cA[2 * NQ];
    float4 cB[2 * NQ];
#pragma unroll
    for (int q = 0; q < NQ; ++q) {
        int j4 = q * TPB + tid;
        pi[q]         = pidx4[j4];
        cA[2 * q]     = pA4[2 * j4];
        cA[2 * q + 1] = pA4[2 * j4 + 1];
        cB[2 * q]     = pB4[2 * j4];
        cB[2 * q + 1] = pB4[2 * j4 + 1];
    }
    MEMFENCE();   // coeff loads issued before DMA(0)/DMA(1): FIFO math stays exact

    // ---- prologue: DMA rows 0,1 -> buf0,buf1 ----
#pragma unroll
    for (int p = 0; p < 2; ++p) {
        const float* xr = x + (size_t)(row0 + p) * IN_DIM;
#pragma unroll
        for (int i = 0; i < NSTG; ++i)
            GLOAD_LDS16(xr + 4 * (i * TPB + tid), &xrow[p][4 * (i * TPB + tid)]);
    }
    MEMFENCE();

#pragma unroll
    for (int r = 0; r < RPB; ++r) {
        // bar_A: every wave finished READING buf[(r+2)%3] (row r-1, iter r-1)
        __builtin_amdgcn_s_barrier();

        // depth-2 prefetch: issue row r+2's DMA before waiting on row r's
        if (r + 2 < RPB) {
            const float* xn = x + (size_t)(row0 + r + 2) * IN_DIM;
#pragma unroll
            for (int i = 0; i < NSTG; ++i)
                GLOAD_LDS16(xn + 4 * (i * TPB + tid),
                            &xrow[(r + 2) % NBUF][4 * (i * TPB + tid)]);
        }
        MEMFENCE();

        // counted retire of DMA(r) only (see table in header comment)
        if      (r == 0)       asm volatile("s_waitcnt vmcnt(4)" ::: "memory");
        else if (r == 1)       asm volatile("s_waitcnt vmcnt(6)" ::: "memory");
        else if (r <= RPB - 3) asm volatile("s_waitcnt vmcnt(8)" ::: "memory");
        else if (r == RPB - 2) asm volatile("s_waitcnt vmcnt(6)" ::: "memory");
        else                   asm volatile("s_waitcnt vmcnt(4)" ::: "memory");
        __builtin_amdgcn_s_barrier();   // bar_B: LDS row r valid for all waves
        MEMFENCE();

        const char* xb = (const char*)xrow[r % NBUF];
        fvec4* out4 = (fvec4*)(out + (size_t)(row0 + r) * OUT_DIM);

#pragma unroll
        for (int q = 0; q < NQ; ++q) {
            int4 p = pi[q];
            // byte-offset gathers (pidx holds idx*4 packed in 16-bit halves)
            float a0 = *(const float*)(xb + (p.x & 0xffff)), b0 = *(const float*)(xb + ((unsigned)p.x >> 16));
            float a1 = *(const float*)(xb + (p.y & 0xffff)), b1 = *(const float*)(xb + ((unsigned)p.y >> 16));
            float a2 = *(const float*)(xb + (p.z & 0xffff)), b2 = *(const float*)(xb + ((unsigned)p.z >> 16));
            float a3 = *(const float*)(xb + (p.w & 0xffff)), b3 = *(const float*)(xb + ((unsigned)p.w >> 16));

            float4 A0 = cA[2 * q], A1 = cA[2 * q + 1];
            float4 B0 = cB[2 * q], B1 = cB[2 * q + 1];

            // o = (c0 + ca*a) + b*(cb + cab*a)   -- 3 FMAs per output
            fvec4 o;
            o.x = fmaf(fmaf(B0.y, a0, B0.x), b0, fmaf(A0.y, a0, A0.x));
            o.y = fmaf(fmaf(B0.w, a1, B0.z), b1, fmaf(A0.w, a1, A0.z));
            o.z = fmaf(fmaf(B1.y, a2, B1.x), b2, fmaf(A1.y, a2, A1.x));
            o.w = fmaf(fmaf(B1.w, a3, B1.z), b3, fmaf(A1.w, a3, A1.z));
            __builtin_nontemporal_store(o, &out4[q * TPB + tid]);
        }
        MEMFENCE();
    }
}

extern "C" void kernel_launch(void* const* d_in, const int* in_sizes, int n_in,
                              void* d_out, int out_size, void* d_ws, size_t ws_size,
                              hipStream_t stream)
{
    const float* x       = (const float*)d_in[0];  // (2048, 8192) fp32
    const float* weights = (const float*)d_in[1];  // (8192, 16)   fp32
    const int*   idx_a   = (const int*)d_in[2];    // (8192,) int32 on device
    const int*   idx_b   = (const int*)d_in[3];    // (8192,) int32 on device
    float* out = (float*)d_out;                    // (2048, 8192) fp32

    int*    pidx = (int*)d_ws;                     // 32 KB
    float2* pcA  = (float2*)(pidx + OUT_DIM);      // 64 KB
    float2* pcB  = pcA + OUT_DIM;                  // 64 KB

    coeff_kernel<<<OUT_DIM / 64, 64, 0, stream>>>(weights, idx_a, idx_b, pidx, pcA, pcB);
    logic_kernel<<<BATCH / RPB, TPB, 0, stream>>>(x, pidx, pcA, pcB, out);
}